// Round 3
// baseline (453.895 us; speedup 1.0000x reference)
//
#include <hip/hip_runtime.h>

// out[b][o] = sum_k x[b][k] * W[o][k] + bias[o]
// M=16, K=8192, N=8192 fp32. HBM-bound on the W stream (256 MiB).
//
// Design: NO LDS, NO barriers. x (512 KB) is L1/L2-resident -> read directly
// from global per chunk (16 KB chunk working set fits L1). W streamed with a
// one-chunk register prefetch so loads stay in flight across the whole loop.
// 2 output rows per wave, 8 per WG, 1024 WGs; occupancy bounded only by VGPRs.

#define B_DIM 16
#define K_DIM 8192
#define N_DIM 8192
#define BK    256                 // k per chunk (64 lanes x float4)
#define BN    8                   // output rows per WG (2 per wave)
#define NTHREADS 256
#define NCHUNK (K_DIM / BK)       // 32

__global__ __launch_bounds__(NTHREADS, 6)
void qlin_gemm(const float* __restrict__ x, const float* __restrict__ w,
               const float* __restrict__ bias, float* __restrict__ out) {
    const int tid  = threadIdx.x;
    const int wid  = tid >> 6;
    const int lane = tid & 63;
    const int o0   = blockIdx.x * BN + wid * 2;    // this wave's 2 output rows

    const float* wrow0 = w + (size_t)o0 * K_DIM;
    const float* wrow1 = wrow0 + K_DIM;

    float acc0[B_DIM], acc1[B_DIM];
#pragma unroll
    for (int b = 0; b < B_DIM; ++b) { acc0[b] = 0.f; acc1[b] = 0.f; }

    // prologue: W for chunk 0
    float4 wq0 = *(const float4*)(wrow0 + lane * 4);
    float4 wq1 = *(const float4*)(wrow1 + lane * 4);

    for (int c = 0; c < NCHUNK; ++c) {
        // prefetch next chunk's W (stays in flight through this chunk's FMAs;
        // no barriers anywhere, so vmcnt never drains to 0 until use)
        float4 nq0, nq1;
        if (c + 1 < NCHUNK) {
            const int kn = (c + 1) * BK + lane * 4;
            nq0 = *(const float4*)(wrow0 + kn);
            nq1 = *(const float4*)(wrow1 + kn);
        }

        // x chunk straight from cache: 16 float4 per lane, L1-hot
        const float* xc = x + c * BK + lane * 4;
#pragma unroll
        for (int b = 0; b < B_DIM; ++b) {
            const float4 xv = *(const float4*)(xc + (size_t)b * K_DIM);
            acc0[b] = fmaf(wq0.x, xv.x, acc0[b]);
            acc0[b] = fmaf(wq0.y, xv.y, acc0[b]);
            acc0[b] = fmaf(wq0.z, xv.z, acc0[b]);
            acc0[b] = fmaf(wq0.w, xv.w, acc0[b]);
            acc1[b] = fmaf(wq1.x, xv.x, acc1[b]);
            acc1[b] = fmaf(wq1.y, xv.y, acc1[b]);
            acc1[b] = fmaf(wq1.z, xv.z, acc1[b]);
            acc1[b] = fmaf(wq1.w, xv.w, acc1[b]);
        }

        wq0 = nq0; wq1 = nq1;   // garbage on last iter, never used
    }

    // butterfly-reduce each accumulator across the 64 lanes
#pragma unroll
    for (int b = 0; b < B_DIM; ++b) {
#pragma unroll
        for (int m = 32; m >= 1; m >>= 1) {
            acc0[b] += __shfl_xor(acc0[b], m, 64);
            acc1[b] += __shfl_xor(acc1[b], m, 64);
        }
    }

    // lane b writes row0, lane 16+b writes row1 (static reg indices only)
#pragma unroll
    for (int b = 0; b < B_DIM; ++b) {
        if (lane == b)      out[(size_t)b * N_DIM + o0]     = acc0[b] + bias[o0];
        if (lane == 16 + b) out[(size_t)b * N_DIM + o0 + 1] = acc1[b] + bias[o0 + 1];
    }
}

extern "C" void kernel_launch(void* const* d_in, const int* in_sizes, int n_in,
                              void* d_out, int out_size, void* d_ws, size_t ws_size,
                              hipStream_t stream) {
    const float* x    = (const float*)d_in[0];   // [16, 8192]
    const float* w    = (const float*)d_in[1];   // [8192, 8192]
    const float* bias = (const float*)d_in[2];   // [8192]
    // d_in[3] = alpha (forward is a plain GEMM; alpha only affects backward)
    float* out = (float*)d_out;                  // [16, 8192]

    dim3 grid(N_DIM / BN);                       // 1024 WGs
    qlin_gemm<<<grid, NTHREADS, 0, stream>>>(x, w, bias, out);
}